// Round 10
// baseline (647.451 us; speedup 1.0000x reference)
//
#include <hip/hip_runtime.h>
#include <stdint.h>

// VCSMC: N=16 taxa, K=128 particles, S=512 sites, A=4, D=64, 15 rounds.
// Bit-exact threefry (partitionable) + order-faithful float32 so all argmax
// decisions match the JAX reference. Round 10: round-6 base (proven 504us) +
// (a) PRNG/proposal precompute tables (r9-verified bits), (b) NO st staging:
// tid0 folds old rows directly from global via indirect 8-deep prefetch
// (same chain order -> bit-identical), (c) ew fused into phase-3 wave 0.
// LDS ~4KB, no staging machinery. r9's felb/slb staging + 3x-inline removed
// (caused 24K bank conflicts + code bloat -> 628us).

#define NN 16
#define KK 128
#define SS 512
#define NR 15
#define PARTITIONABLE 1
#define TINYF 1.17549435e-38f
#define NROWS (NN + NR * KK)   // 1936 pool rows

// ---------------- threefry2x32 (JAX-exact) ----------------
__host__ __device__ __forceinline__ void tf2x32(uint32_t k0, uint32_t k1,
                                                uint32_t c0, uint32_t c1,
                                                uint32_t* o0, uint32_t* o1) {
  uint32_t ks2 = k0 ^ k1 ^ 0x1BD11BDAu;
  uint32_t x0 = c0 + k0, x1 = c1 + k1;
  uint32_t ks[3] = {k0, k1, ks2};
  const uint32_t RA[4] = {13u, 15u, 26u, 6u};
  const uint32_t RB[4] = {17u, 29u, 16u, 24u};
#pragma unroll
  for (int i = 0; i < 5; ++i) {
#pragma unroll
    for (int j = 0; j < 4; ++j) {
      uint32_t r = (i & 1) ? RB[j] : RA[j];
      x0 += x1;
      x1 = (x1 << r) | (x1 >> (32u - r));
      x1 ^= x0;
    }
    x0 += ks[(i + 1) % 3];
    x1 += ks[(i + 2) % 3] + (uint32_t)(i + 1);
  }
  *o0 = x0; *o1 = x1;
}

__device__ __forceinline__ uint32_t rbits32(uint32_t ka, uint32_t kb,
                                            uint32_t i, uint32_t total) {
#if PARTITIONABLE
  uint32_t o0, o1;
  tf2x32(ka, kb, 0u, i, &o0, &o1);
  return o0 ^ o1;
#else
  uint32_t half = total >> 1;
  uint32_t o0, o1;
  if (i < half) { tf2x32(ka, kb, i, i + half, &o0, &o1); return o0; }
  tf2x32(ka, kb, i - half, i, &o0, &o1);
  return o1;
#endif
}

__device__ __forceinline__ float bits_unif(uint32_t b) {
  return __uint_as_float((b >> 9) | 0x3f800000u) - 1.0f;  // [0,1)
}

// XLA CPU fast-tanh (with_fma=false) replicated.
__device__ __forceinline__ float xla_tanh(float x) {
  float ax = fabsf(x);
  float xc = fminf(fmaxf(x, -7.90531110763549805f), 7.90531110763549805f);
  float x2 = __fmul_rn(xc, xc);
  float num = -2.76076847742355e-16f;
  num = __fadd_rn(__fmul_rn(x2, num), 2.00018790482477e-13f);
  num = __fadd_rn(__fmul_rn(x2, num), -8.60467152213735e-11f);
  num = __fadd_rn(__fmul_rn(x2, num), 5.12229709037114e-08f);
  num = __fadd_rn(__fmul_rn(x2, num), 1.48572235717979e-05f);
  num = __fadd_rn(__fmul_rn(x2, num), 6.37261928875436e-04f);
  num = __fadd_rn(__fmul_rn(x2, num), 4.89352455891786e-03f);
  num = __fmul_rn(xc, num);
  float den = 1.19825839466702e-06f;
  den = __fadd_rn(__fmul_rn(x2, den), 1.18534705686654e-04f);
  den = __fadd_rn(__fmul_rn(x2, den), 2.26843463243900e-03f);
  den = __fadd_rn(__fmul_rn(x2, den), 4.89352518554385e-03f);
  float r = __fdiv_rn(num, den);
  return (ax < 0.0004f) ? x : r;
}

__device__ __forceinline__ float fin_or0(float v) {
  return (v > -INFINITY && v < INFINITY) ? v : 0.0f;
}

// exact ordered left-fold of n4 float4s (n4 multiple of 8), 8-deep prefetch
__device__ __forceinline__ void fold8(float& ll, const float4* b4, int n4) {
  if (n4 <= 0) return;
  float4 pre[8];
#pragma unroll
  for (int i = 0; i < 8; ++i) pre[i] = b4[i];
  for (int q = 8; q <= n4; q += 8) {
    float4 cur[8];
#pragma unroll
    for (int i = 0; i < 8; ++i) cur[i] = pre[i];
    if (q < n4) {
#pragma unroll
      for (int i = 0; i < 8; ++i) pre[i] = b4[q + i];
    }
#pragma unroll
    for (int i = 0; i < 8; ++i) {
      ll = __fadd_rn(ll, cur[i].x);
      ll = __fadd_rn(ll, cur[i].y);
      ll = __fadd_rn(ll, cur[i].z);
      ll = __fadd_rn(ll, cur[i].w);
    }
  }
}

// same fold, rows addressed indirectly via ilN (LDS); identical chain order.
__device__ __forceinline__ void fold_ind(float& ll, const float* st_pool,
                                         const int* ilN, int n4) {
  if (n4 <= 0) return;
  float4 pre[8];
#pragma unroll
  for (int i = 0; i < 8; ++i)
    pre[i] = *((const float4*)(st_pool + (size_t)ilN[i >> 7] * 512) + (i & 127));
  for (int q = 8; q <= n4; q += 8) {
    float4 cur[8];
#pragma unroll
    for (int i = 0; i < 8; ++i) cur[i] = pre[i];
    if (q < n4) {
#pragma unroll
      for (int i = 0; i < 8; ++i) {
        int qq = q + i;
        pre[i] = *((const float4*)(st_pool + (size_t)ilN[qq >> 7] * 512) + (qq & 127));
      }
    }
#pragma unroll
    for (int i = 0; i < 8; ++i) {
      ll = __fadd_rn(ll, cur[i].x);
      ll = __fadd_rn(ll, cur[i].y);
      ll = __fadd_rn(ll, cur[i].z);
      ll = __fadd_rn(ll, cur[i].w);
    }
  }
}

struct KeysAll { uint32_t v[NR][8]; };

// ---------------- setup ----------------
// blocks 0..63: leaf fel rows; 64..71: site logits; 72: misc init;
// 73..1032: gumbel table (15*128*128); 1033..1040: proposal table (15*128)
__global__ void k_setup(KeysAll keys, const float* datab, const float* Wpos,
                        const float* Wsite, float* fel_pool, float* sitelog,
                        float* logw0, float* logpi0, int* lc_pool, int* ilist0,
                        float* logdf, float* gtab, int* pidx1, int* pidx2,
                        float* pb1, float* pb2, float* plvp, float* pee1,
                        float* pee2) {
  int b = blockIdx.x, tid = threadIdx.x;
  if (b < 64) {
    int id = b * 256 + tid;
    fel_pool[id] = logf(datab[id]);
    fel_pool[16384 + id] = logf(datab[16384 + id]);
  } else if (b < 72) {
    int id = (b - 64) * 256 + tid;  // 2048
    int s = id >> 2, aa = id & 3;
    float acc = 0.0f;
    for (int c = 0; c < 16; ++c) acc = fmaf(Wpos[s * 16 + c], Wsite[c * 4 + aa], acc);
    sitelog[id] = acc;
  } else if (b == 72) {
    if (tid < KK) {
      logw0[tid] = 0.0f;
      logpi0[tid] = 0.0f;
      for (int nn2 = 0; nn2 < NN; ++nn2) ilist0[tid * 16 + nn2] = nn2;
    }
    if (tid < NN) lc_pool[tid] = 1;
    if (tid == 0) {
      double vv[33];
      vv[0] = 0.0; vv[1] = 0.0;
      for (int i = 2; i <= 32; ++i) vv[i] = vv[i - 2] + log((double)i);
      for (int i = 0; i < 33; ++i) logdf[i] = (float)vv[i];
    }
  } else if (b < 1033) {
    // gumbel table: exact same ops as the in-round phase 1 of rounds 1-6
    int gi = (b - 73) * 256 + tid;       // 0..245759
    int r = gi >> 14;                    // /16384
    uint32_t rem = (uint32_t)(gi & 16383);  // i*128+j
    uint32_t bits = rbits32(keys.v[r][0], keys.v[r][1], rem, KK * KK);
    float f = bits_unif(bits);
    float u = fmaxf(TINYF, __fadd_rn(f, TINYF));
    gtab[gi] = -logf(-logf(u));
  } else {
    // proposal table: exact same ops as the in-round tid==128 block
    int gi = (b - 1033) * 256 + tid;     // 0..2047
    if (gi < NR * KK) {
      int r = gi >> 7, k = gi & 127;
      int t = NN - r;
      uint32_t h = rbits32(keys.v[r][2], keys.v[r][3], (uint32_t)k, 256u);
      uint32_t l = rbits32(keys.v[r][2], keys.v[r][3], (uint32_t)(128 + k), 256u);
      uint32_t span = (uint32_t)(t * (t - 1) / 2);
      uint32_t mult = 65536u % span;
      mult = (mult * mult) % span;
      uint32_t off = ((h % span) * mult + (l % span)) % span;
      int p = (int)off;
      int a1 = 0, rem = p, rl = t - 1;
      while (rem >= rl) { rem -= rl; ++a1; --rl; }
      pidx1[gi] = a1;
      pidx2[gi] = a1 + 1 + rem;
      uint32_t bb = rbits32(keys.v[r][4], keys.v[r][5], (uint32_t)k, 128u);
      float e1 = -log1pf(-bits_unif(bb));
      bb = rbits32(keys.v[r][6], keys.v[r][7], (uint32_t)k, 128u);
      float e2 = -log1pf(-bits_unif(bb));
      pb1[gi] = e1; pb2[gi] = e2;
      float lnp = logf((float)span);
      plvp[gi] = __fadd_rn(__fadd_rn(-lnp, -e1), -e2);
      pee1[gi] = expf(-e1);
      pee2[gi] = expf(-e2);
    }
  }
}

// seq_encoder: lane d computes emb(n,d) with the exact sequential fmaf chain.
__global__ __launch_bounds__(64) void k_emb0(const float* data, const float* Wenc,
                                             const float* Wstat, float* emb_pool,
                                             float* ew0) {
  int n = blockIdx.x, d = threadIdx.x;
  __shared__ float ne[64];
  const float* dp = data + n * 2048;
  const float* wp = Wenc + d;
  float acc = 0.0f;
#pragma unroll 32
  for (int i = 0; i < 2048; ++i) acc = fmaf(dp[i], wp[(size_t)i * 64], acc);
  float v = xla_tanh(acc);
  ne[d] = v;
  emb_pool[n * 64 + d] = v;
  __syncthreads();
  if (d < 4) {
    float s = 0.0f;
    for (int c = 0; c < 64; ++c) s = fmaf(ne[c], Wstat[c * 4 + d], s);
    ew0[n * 4 + d] = s;
  }
}

__global__ void k_leafterm(const float* fel_pool, const float* ew0,
                           const float* sitelog, float* st_pool) {
  int id = blockIdx.x * blockDim.x + threadIdx.x;
  if (id >= NN * SS) return;
  int n = id >> 9, s = id & 511;
  float lg[4], ex[4], stat[4];
  for (int a = 0; a < 4; ++a) lg[a] = __fadd_rn(ew0[n * 4 + a], sitelog[s * 4 + a]);
  float m = lg[0];
  for (int a = 1; a < 4; ++a) m = fmaxf(m, lg[a]);
  float ssum = 0.0f;
  for (int a = 0; a < 4; ++a) { ex[a] = expf(__fsub_rn(lg[a], m)); ssum = __fadd_rn(ssum, ex[a]); }
  for (int a = 0; a < 4; ++a) stat[a] = __fdiv_rn(ex[a], ssum);
  float q[4], am = -INFINITY;
  for (int a = 0; a < 4; ++a) {
    q[a] = __fadd_rn(fel_pool[n * 2048 + s * 4 + a], logf(stat[a]));
    am = fmaxf(am, q[a]);
  }
  am = fin_or0(am);
  float se = 0.0f;
  for (int a = 0; a < 4; ++a) se = __fadd_rn(se, expf(__fsub_rn(q[a], am)));
  st_pool[n * 512 + s] = __fadd_rn(logf(se), am);
}

// ---------------- the fused per-round kernel (256 threads) ----------------
__global__ __launch_bounds__(256) void k_round(
    int t, int r,
    const float* gtab, const int* pidx1, const int* pidx2,
    const float* pb1, const float* pb2, const float* plvp,
    const float* pee1, const float* pee2,
    const float* logwC, float* logwN,
    const float* logpiC, float* logpiN,
    const int* ilistC, int* ilistN,
    const int* m1C, int* m1N, const int* m2C, int* m2N,
    const float* br1C, float* br1N, const float* br2C, float* br2N,
    float* emb_pool, float* fel_pool, float* st_pool, int* lc_pool,
    const float* Wmerge, const float* Wstat, const float* sitelog,
    const float* logdf, float* logws_r, float* loglik) {
  int k = blockIdx.x, tid = threadIdx.x;
  int tn = t - 1, tn2 = t - 2;
  int newrow = NN + r * KK + k;
  __shared__ float stnew[512];          // new st row (2 KB)
  __shared__ float cat[128];
  __shared__ float ne[64];
  __shared__ float ewl[4];
  __shared__ float smax[4];
  __shared__ int sidx[4];
  __shared__ int sI1, sI2;
  __shared__ float sB1, sB2, sLvp, sE1, sE2;
  __shared__ int ilN[16];
  __shared__ int lcb[16];
  __shared__ float brb1[15], brb2[15];

  // ---- phase 1: resample argmax (gumbels precomputed) + proposal loads ----
  float v = -INFINITY;
  if (tid < 128) {
    v = __fadd_rn(gtab[((size_t)r * KK + k) * KK + tid], logwC[tid]);
  } else if (tid == 128) {
    int gi = r * KK + k;
    sI1 = pidx1[gi];
    sI2 = pidx2[gi];
    sB1 = pb1[gi];
    sB2 = pb2[gi];
    sLvp = plvp[gi];
    sE1 = pee1[gi];
    sE2 = pee2[gi];
  }
  float m = v;
  for (int d = 32; d > 0; d >>= 1) m = fmaxf(m, __shfl_xor(m, d, 64));
  int w = tid >> 6;
  if ((tid & 63) == 0) smax[w] = m;
  __syncthreads();
  float gm = fmaxf(fmaxf(smax[0], smax[1]), fmaxf(smax[2], smax[3]));
  int cand = (v == gm) ? tid : 9999;
  for (int d = 32; d > 0; d >>= 1) {
    int o = __shfl_xor(cand, d, 64);
    cand = (o < cand) ? o : cand;
  }
  if ((tid & 63) == 0) sidx[w] = cand;
  __syncthreads();
  int a;
  {
    int b0 = (sidx[0] < sidx[1]) ? sidx[0] : sidx[1];
    int b1_ = (sidx[2] < sidx[3]) ? sidx[2] : sidx[3];
    a = (b0 < b1_) ? b0 : b1_;
  }
  int i1 = sI1, i2 = sI2;
  int p1 = ilistC[a * 16 + i1];
  int p2 = ilistC[a * 16 + i2];

  // ---- phase 2: cat load | bookkeeping ----
  if (tid < 64) {
    cat[tid] = emb_pool[p1 * 64 + tid];
    cat[64 + tid] = emb_pool[p2 * 64 + tid];
  } else if (tid >= 64 && tid < 80) {
    int pos = tid - 64;
    if (pos < tn2) {
      int src = pos + (pos >= i1) + (pos >= (i2 - 1));
      int row = ilistC[a * 16 + src];
      ilN[pos] = row;
      ilistN[k * 16 + pos] = row;
      lcb[pos] = lc_pool[row];
    } else if (pos == tn2) {
      ilN[pos] = newrow;
      ilistN[k * 16 + pos] = newrow;
      int lcnew = lc_pool[p1] + lc_pool[p2];
      lcb[pos] = lcnew;
      lc_pool[newrow] = lcnew;
    }
  } else if (tid >= 96 && tid < 96 + NR) {
    int j = tid - 96;
    if (j < r) {
      int v1 = m1C[a * 15 + j]; m1N[k * 15 + j] = v1;
      int v2 = m2C[a * 15 + j]; m2N[k * 15 + j] = v2;
      float w1 = br1C[a * 15 + j]; br1N[k * 15 + j] = w1; brb1[j] = w1;
      float w2 = br2C[a * 15 + j]; br2N[k * 15 + j] = w2; brb2[j] = w2;
    } else if (j == r) {
      m1N[k * 15 + r] = i1;
      m2N[k * 15 + r] = i2;
      br1N[k * 15 + r] = sB1;
      br2N[k * 15 + r] = sB2;
      brb1[r] = sB1;
      brb2[r] = sB2;
    }
  }
  __syncthreads();

  // ---- phase 3: newemb + ew (wave 0 only; same-wave LDS ordering) ----
  if (tid < 64) {
    float acc = 0.0f;
    for (int c = 0; c < 128; ++c) acc = fmaf(cat[c], Wmerge[c * 64 + tid], acc);
    float vv = xla_tanh(acc);
    ne[tid] = vv;
    emb_pool[newrow * 64 + tid] = vv;
    if (tid < 4) {
      float s = 0.0f;
      for (int c = 0; c < 64; ++c) s = fmaf(ne[c], Wstat[c * 4 + tid], s);
      ewl[tid] = s;
    }
  }
  __syncthreads();

  // ---- phase 5: fold old rows from global (tid 0) || Felsenstein sites ----
  float ll = 0.0f;
  if (tid == 0) {
    fold_ind(ll, st_pool, ilN, tn2 * 128);
  } else if (tid >= 64) {
    float e1 = sE1, e2 = sE2;
    float om1 = __fsub_rn(1.0f, e1), om2 = __fsub_rn(1.0f, e2);
    float ewv[4];
#pragma unroll
    for (int aa = 0; aa < 4; ++aa) ewv[aa] = ewl[aa];
    for (int s = tid - 64; s < 512; s += 192) {
      float lg[4], ex[4], stat[4];
#pragma unroll
      for (int aa = 0; aa < 4; ++aa) lg[aa] = __fadd_rn(ewv[aa], sitelog[s * 4 + aa]);
      float mm = lg[0];
#pragma unroll
      for (int aa = 1; aa < 4; ++aa) mm = fmaxf(mm, lg[aa]);
      float ssum = 0.0f;
#pragma unroll
      for (int aa = 0; aa < 4; ++aa) {
        ex[aa] = expf(__fsub_rn(lg[aa], mm));
        ssum = __fadd_rn(ssum, ex[aa]);
      }
#pragma unroll
      for (int aa = 0; aa < 4; ++aa) stat[aa] = __fdiv_rn(ex[aa], ssum);
      float4 f1v = *(const float4*)(fel_pool + (size_t)p1 * 2048 + s * 4);
      float4 f2v = *(const float4*)(fel_pool + (size_t)p2 * 2048 + s * 4);
      float f1a[4] = {f1v.x, f1v.y, f1v.z, f1v.w};
      float f2a[4] = {f2v.x, f2v.y, f2v.z, f2v.w};
      // deduped log P (bitwise-identical inputs; see rounds 5/6)
      float lo1[4], ld1[4], lo2[4], ld2[4];
#pragma unroll
      for (int bb = 0; bb < 4; ++bb) {
        float m1v = __fmul_rn(om1, stat[bb]);
        lo1[bb] = logf(__fadd_rn(m1v, 1e-30f));
        ld1[bb] = logf(__fadd_rn(__fadd_rn(e1, m1v), 1e-30f));
        float m2v = __fmul_rn(om2, stat[bb]);
        lo2[bb] = logf(__fadd_rn(m2v, 1e-30f));
        ld2[bb] = logf(__fadd_rn(__fadd_rn(e2, m2v), 1e-30f));
      }
      float nf[4];
#pragma unroll
      for (int aa = 0; aa < 4; ++aa) {
        float q1[4], am = -INFINITY;
#pragma unroll
        for (int bb = 0; bb < 4; ++bb) {
          q1[bb] = __fadd_rn((aa == bb) ? ld1[bb] : lo1[bb], f1a[bb]);
          am = fmaxf(am, q1[bb]);
        }
        am = fin_or0(am);
        float se = 0.0f;
#pragma unroll
        for (int bb = 0; bb < 4; ++bb) se = __fadd_rn(se, expf(__fsub_rn(q1[bb], am)));
        float h1 = __fadd_rn(logf(se), am);
        float q2[4], am2 = -INFINITY;
#pragma unroll
        for (int bb = 0; bb < 4; ++bb) {
          q2[bb] = __fadd_rn((aa == bb) ? ld2[bb] : lo2[bb], f2a[bb]);
          am2 = fmaxf(am2, q2[bb]);
        }
        am2 = fin_or0(am2);
        float se2 = 0.0f;
#pragma unroll
        for (int bb = 0; bb < 4; ++bb) se2 = __fadd_rn(se2, expf(__fsub_rn(q2[bb], am2)));
        float h2 = __fadd_rn(logf(se2), am2);
        nf[aa] = __fadd_rn(h1, h2);
      }
      *(float4*)(fel_pool + (size_t)newrow * 2048 + s * 4) =
          make_float4(nf[0], nf[1], nf[2], nf[3]);
      float q3[4], am3 = -INFINITY;
#pragma unroll
      for (int aa = 0; aa < 4; ++aa) {
        q3[aa] = __fadd_rn(nf[aa], logf(stat[aa]));
        am3 = fmaxf(am3, q3[aa]);
      }
      am3 = fin_or0(am3);
      float se3 = 0.0f;
#pragma unroll
      for (int aa = 0; aa < 4; ++aa) se3 = __fadd_rn(se3, expf(__fsub_rn(q3[aa], am3)));
      float stv = __fadd_rn(logf(se3), am3);
      stnew[s] = stv;
      st_pool[(size_t)newrow * 512 + s] = stv;
    }
  }
  __syncthreads();

  // ---- phase 6: fold new row + weights (tid 0) ----
  if (tid == 0) {
    fold8(ll, (const float4*)stnew, 128);
    float lt = 0.0f;
    for (int pos = 0; pos < tn; ++pos) {
      int idx = 2 * lcb[pos] - 3;
      if (idx < 0) idx = 0;
      lt = __fadd_rn(lt, logdf[idx]);
    }
    lt = -lt;
    float s1 = 0.0f, s2 = 0.0f;
    for (int j = 0; j <= r; ++j) {
      s1 = __fadd_rn(s1, -brb1[j]);
      s2 = __fadd_rn(s2, -brb2[j]);
    }
    float lb = __fadd_rn(s1, s2);
    float lpi = __fadd_rn(__fadd_rn(ll, lt), lb);
    float prev = logpiC[a];
    float lw = __fsub_rn(__fadd_rn(__fsub_rn(lpi, prev), 0.0f), sLvp);
    logpiN[k] = lpi;
    logwN[k] = lw;
    logws_r[k] = lw;
    loglik[k] = ll;
  }
}

// final: parallel. Exact max / first-argmax; parallel exp-sum only hits out[0].
__global__ void k_final(const float* logws, const float* loglik,
                        const int* m1D, const int* m2D,
                        const float* br1D, const float* br2D, float* out) {
  int j = threadIdx.x;  // 128
  out[1 + j] = loglik[j];
  __shared__ float sm[2];
  __shared__ float ssum[2];
  __shared__ int si[2];
  float c = logf(128.0f);
  float z = 0.0f;
  for (int r = 0; r < NR; ++r) {
    float v = __fsub_rn(logws[r * KK + j], c);
    float m = v;
    for (int d = 32; d > 0; d >>= 1) m = fmaxf(m, __shfl_xor(m, d, 64));
    if ((j & 63) == 0) sm[j >> 6] = m;
    __syncthreads();
    float gm = fin_or0(fmaxf(sm[0], sm[1]));
    float e = expf(__fsub_rn(v, gm));
    for (int d = 32; d > 0; d >>= 1) e = __fadd_rn(e, __shfl_xor(e, d, 64));
    if ((j & 63) == 0) ssum[j >> 6] = e;
    __syncthreads();
    if (j == 0) z = __fadd_rn(z, __fadd_rn(logf(__fadd_rn(ssum[0], ssum[1])), gm));
    __syncthreads();
  }
  if (j == 0) out[0] = z;
  float lv = loglik[j];
  float m2 = lv;
  for (int d = 32; d > 0; d >>= 1) m2 = fmaxf(m2, __shfl_xor(m2, d, 64));
  if ((j & 63) == 0) sm[j >> 6] = m2;
  __syncthreads();
  float gm2 = fmaxf(sm[0], sm[1]);
  int cand = (lv == gm2) ? j : 9999;
  for (int d = 32; d > 0; d >>= 1) {
    int o = __shfl_xor(cand, d, 64);
    cand = (o < cand) ? o : cand;
  }
  if ((j & 63) == 0) si[j >> 6] = cand;
  __syncthreads();
  int bi = (si[0] < si[1]) ? si[0] : si[1];
  if (j < NR) {
    out[129 + j] = (float)m1D[bi * 15 + j];
    out[144 + j] = (float)m2D[bi * 15 + j];
    out[159 + j] = br1D[bi * 15 + j];
    out[174 + j] = br2D[bi * 15 + j];
  }
}

// ---------------- host: key schedule + orchestration ----------------
static void split5_host(uint32_t* key0, uint32_t* key1, uint32_t out[8]) {
#if PARTITIONABLE
  uint32_t nk0, nk1, o0, o1;
  tf2x32(*key0, *key1, 0u, 0u, &nk0, &nk1);
  for (int j = 1; j < 5; ++j) {
    tf2x32(*key0, *key1, 0u, (uint32_t)j, &o0, &o1);
    out[2 * (j - 1)] = o0;
    out[2 * (j - 1) + 1] = o1;
  }
  *key0 = nk0; *key1 = nk1;
#else
  uint32_t a0[5], a1[5];
  for (int i = 0; i < 5; ++i) tf2x32(*key0, *key1, (uint32_t)i, (uint32_t)(i + 5), &a0[i], &a1[i]);
  uint32_t flat[10] = {a0[0], a0[1], a0[2], a0[3], a0[4], a1[0], a1[1], a1[2], a1[3], a1[4]};
  *key0 = flat[0]; *key1 = flat[1];
  for (int j = 0; j < 8; ++j) out[j] = flat[2 + j];
#endif
}

extern "C" void kernel_launch(void* const* d_in, const int* in_sizes, int n_in,
                              void* d_out, int out_size, void* d_ws, size_t ws_size,
                              hipStream_t stream) {
  const float* data = (const float*)d_in[0];
  const float* datab = (const float*)d_in[1];
  const float* Wenc = (const float*)d_in[3];
  const float* Wmerge = (const float*)d_in[4];
  const float* Wstat = (const float*)d_in[5];
  const float* Wpos = (const float*)d_in[6];
  const float* Wsite = (const float*)d_in[7];
  float* out = (float*)d_out;

  char* base = (char*)d_ws;
  size_t off = 0;
  auto alloc = [&](size_t bytes) -> void* {
    void* p = base + off;
    off += (bytes + 255) & ~(size_t)255;
    return p;
  };
  float* fel_pool = (float*)alloc((size_t)NROWS * 2048 * 4);
  float* st_pool = (float*)alloc((size_t)NROWS * 512 * 4);
  float* emb_pool = (float*)alloc((size_t)NROWS * 64 * 4);
  int* lc_pool = (int*)alloc((size_t)NROWS * 4);
  int* ilist[2]; int* m1[2]; int* m2[2]; float* br1[2]; float* br2[2];
  float* logpi[2]; float* logw2[2];
  for (int b = 0; b < 2; ++b) ilist[b] = (int*)alloc((size_t)KK * 16 * 4);
  for (int b = 0; b < 2; ++b) m1[b] = (int*)alloc((size_t)KK * 15 * 4);
  for (int b = 0; b < 2; ++b) m2[b] = (int*)alloc((size_t)KK * 15 * 4);
  for (int b = 0; b < 2; ++b) br1[b] = (float*)alloc((size_t)KK * 15 * 4);
  for (int b = 0; b < 2; ++b) br2[b] = (float*)alloc((size_t)KK * 15 * 4);
  for (int b = 0; b < 2; ++b) logpi[b] = (float*)alloc((size_t)KK * 4);
  for (int b = 0; b < 2; ++b) logw2[b] = (float*)alloc((size_t)KK * 4);
  float* logws = (float*)alloc(NR * KK * 4);
  float* loglik = (float*)alloc(KK * 4);
  float* sitelog = (float*)alloc(SS * 4 * 4);
  float* logdf = (float*)alloc(33 * 4);
  float* ew0 = (float*)alloc(NN * 4 * 4);
  float* gtab = (float*)alloc((size_t)NR * KK * KK * 4);   // 983 KB
  int* pidx1 = (int*)alloc((size_t)NR * KK * 4);
  int* pidx2 = (int*)alloc((size_t)NR * KK * 4);
  float* pb1 = (float*)alloc((size_t)NR * KK * 4);
  float* pb2 = (float*)alloc((size_t)NR * KK * 4);
  float* plvp = (float*)alloc((size_t)NR * KK * 4);
  float* pee1 = (float*)alloc((size_t)NR * KK * 4);
  float* pee2 = (float*)alloc((size_t)NR * KK * 4);
  (void)ws_size; (void)in_sizes; (void)n_in; (void)out_size;

  // precompute all round keys on host (deterministic)
  KeysAll keys;
  uint32_t key0 = 0u, key1 = 42u;  // jax.random.key(42)
  for (int r = 0; r < NR; ++r) split5_host(&key0, &key1, keys.v[r]);

  // setup (3 launches)
  k_setup<<<1041, 256, 0, stream>>>(keys, datab, Wpos, Wsite, fel_pool, sitelog,
                                    logw2[0], logpi[0], lc_pool, ilist[0], logdf,
                                    gtab, pidx1, pidx2, pb1, pb2, plvp, pee1, pee2);
  k_emb0<<<NN, 64, 0, stream>>>(data, Wenc, Wstat, emb_pool, ew0);
  k_leafterm<<<32, 256, 0, stream>>>(fel_pool, ew0, sitelog, st_pool);

  for (int r = 0; r < NR; ++r) {
    int t = NN - r;
    int cur = r & 1, nxt = cur ^ 1;
    k_round<<<KK, 256, 0, stream>>>(
        t, r, gtab, pidx1, pidx2, pb1, pb2, plvp, pee1, pee2,
        logw2[cur], logw2[nxt], logpi[cur], logpi[nxt],
        ilist[cur], ilist[nxt], m1[cur], m1[nxt], m2[cur], m2[nxt],
        br1[cur], br1[nxt], br2[cur], br2[nxt],
        emb_pool, fel_pool, st_pool, lc_pool,
        Wmerge, Wstat, sitelog, logdf, logws + r * KK, loglik);
  }
  // after r=14: nxt == 1
  k_final<<<1, 128, 0, stream>>>(logws, loglik, m1[1], m2[1], br1[1], br2[1], out);
}

// Round 11
// 488.312 us; speedup vs baseline: 1.3259x; 1.3259x over previous
//
#include <hip/hip_runtime.h>
#include <stdint.h>

// VCSMC: N=16 taxa, K=128 particles, S=512 sites, A=4, D=64, 15 rounds.
// Bit-exact threefry (partitionable) + order-faithful float32 so all argmax
// decisions match the JAX reference. Round 11 (consolidation): round-6 body
// VERBATIM (proven 504us: LDS st-staging for the serial fold, 256 threads)
// + only two r9/r10-bit-verified deltas: (a) PRNG/proposal precompute
// tables (phase-1 serial logf chains off the critical path), (b) ew fused
// into phase-3 wave 0 (one less barrier). r10's global-fold removed (put
// HBM latency inside the dependent add chain -> 647us).

#define NN 16
#define KK 128
#define SS 512
#define NR 15
#define PARTITIONABLE 1
#define TINYF 1.17549435e-38f
#define NROWS (NN + NR * KK)   // 1936 pool rows

// ---------------- threefry2x32 (JAX-exact) ----------------
__host__ __device__ __forceinline__ void tf2x32(uint32_t k0, uint32_t k1,
                                                uint32_t c0, uint32_t c1,
                                                uint32_t* o0, uint32_t* o1) {
  uint32_t ks2 = k0 ^ k1 ^ 0x1BD11BDAu;
  uint32_t x0 = c0 + k0, x1 = c1 + k1;
  uint32_t ks[3] = {k0, k1, ks2};
  const uint32_t RA[4] = {13u, 15u, 26u, 6u};
  const uint32_t RB[4] = {17u, 29u, 16u, 24u};
#pragma unroll
  for (int i = 0; i < 5; ++i) {
#pragma unroll
    for (int j = 0; j < 4; ++j) {
      uint32_t r = (i & 1) ? RB[j] : RA[j];
      x0 += x1;
      x1 = (x1 << r) | (x1 >> (32u - r));
      x1 ^= x0;
    }
    x0 += ks[(i + 1) % 3];
    x1 += ks[(i + 2) % 3] + (uint32_t)(i + 1);
  }
  *o0 = x0; *o1 = x1;
}

__device__ __forceinline__ uint32_t rbits32(uint32_t ka, uint32_t kb,
                                            uint32_t i, uint32_t total) {
#if PARTITIONABLE
  uint32_t o0, o1;
  tf2x32(ka, kb, 0u, i, &o0, &o1);
  return o0 ^ o1;
#else
  uint32_t half = total >> 1;
  uint32_t o0, o1;
  if (i < half) { tf2x32(ka, kb, i, i + half, &o0, &o1); return o0; }
  tf2x32(ka, kb, i - half, i, &o0, &o1);
  return o1;
#endif
}

__device__ __forceinline__ float bits_unif(uint32_t b) {
  return __uint_as_float((b >> 9) | 0x3f800000u) - 1.0f;  // [0,1)
}

// XLA CPU fast-tanh (with_fma=false) replicated.
__device__ __forceinline__ float xla_tanh(float x) {
  float ax = fabsf(x);
  float xc = fminf(fmaxf(x, -7.90531110763549805f), 7.90531110763549805f);
  float x2 = __fmul_rn(xc, xc);
  float num = -2.76076847742355e-16f;
  num = __fadd_rn(__fmul_rn(x2, num), 2.00018790482477e-13f);
  num = __fadd_rn(__fmul_rn(x2, num), -8.60467152213735e-11f);
  num = __fadd_rn(__fmul_rn(x2, num), 5.12229709037114e-08f);
  num = __fadd_rn(__fmul_rn(x2, num), 1.48572235717979e-05f);
  num = __fadd_rn(__fmul_rn(x2, num), 6.37261928875436e-04f);
  num = __fadd_rn(__fmul_rn(x2, num), 4.89352455891786e-03f);
  num = __fmul_rn(xc, num);
  float den = 1.19825839466702e-06f;
  den = __fadd_rn(__fmul_rn(x2, den), 1.18534705686654e-04f);
  den = __fadd_rn(__fmul_rn(x2, den), 2.26843463243900e-03f);
  den = __fadd_rn(__fmul_rn(x2, den), 4.89352518554385e-03f);
  float r = __fdiv_rn(num, den);
  return (ax < 0.0004f) ? x : r;
}

__device__ __forceinline__ float fin_or0(float v) {
  return (v > -INFINITY && v < INFINITY) ? v : 0.0f;
}

// exact ordered left-fold of n4 float4s (n4 multiple of 8), 8-deep prefetch
__device__ __forceinline__ void fold8(float& ll, const float4* b4, int n4) {
  if (n4 <= 0) return;
  float4 pre[8];
#pragma unroll
  for (int i = 0; i < 8; ++i) pre[i] = b4[i];
  for (int q = 8; q <= n4; q += 8) {
    float4 cur[8];
#pragma unroll
    for (int i = 0; i < 8; ++i) cur[i] = pre[i];
    if (q < n4) {
#pragma unroll
      for (int i = 0; i < 8; ++i) pre[i] = b4[q + i];
    }
#pragma unroll
    for (int i = 0; i < 8; ++i) {
      ll = __fadd_rn(ll, cur[i].x);
      ll = __fadd_rn(ll, cur[i].y);
      ll = __fadd_rn(ll, cur[i].z);
      ll = __fadd_rn(ll, cur[i].w);
    }
  }
}

struct KeysAll { uint32_t v[NR][8]; };

// ---------------- setup ----------------
// blocks 0..63: leaf fel rows; 64..71: site logits; 72: misc init;
// 73..1032: gumbel table (15*128*128); 1033..1040: proposal table (15*128)
__global__ void k_setup(KeysAll keys, const float* datab, const float* Wpos,
                        const float* Wsite, float* fel_pool, float* sitelog,
                        float* logw0, float* logpi0, int* lc_pool, int* ilist0,
                        float* logdf, float* gtab, int* pidx1, int* pidx2,
                        float* pb1, float* pb2, float* plvp, float* pee1,
                        float* pee2) {
  int b = blockIdx.x, tid = threadIdx.x;
  if (b < 64) {
    int id = b * 256 + tid;
    fel_pool[id] = logf(datab[id]);
    fel_pool[16384 + id] = logf(datab[16384 + id]);
  } else if (b < 72) {
    int id = (b - 64) * 256 + tid;  // 2048
    int s = id >> 2, aa = id & 3;
    float acc = 0.0f;
    for (int c = 0; c < 16; ++c) acc = fmaf(Wpos[s * 16 + c], Wsite[c * 4 + aa], acc);
    sitelog[id] = acc;
  } else if (b == 72) {
    if (tid < KK) {
      logw0[tid] = 0.0f;
      logpi0[tid] = 0.0f;
      for (int nn2 = 0; nn2 < NN; ++nn2) ilist0[tid * 16 + nn2] = nn2;
    }
    if (tid < NN) lc_pool[tid] = 1;
    if (tid == 0) {
      double vv[33];
      vv[0] = 0.0; vv[1] = 0.0;
      for (int i = 2; i <= 32; ++i) vv[i] = vv[i - 2] + log((double)i);
      for (int i = 0; i < 33; ++i) logdf[i] = (float)vv[i];
    }
  } else if (b < 1033) {
    // gumbel table: exact same ops as the in-round phase 1 of rounds 1-6
    int gi = (b - 73) * 256 + tid;       // 0..245759
    int r = gi >> 14;                    // /16384
    uint32_t rem = (uint32_t)(gi & 16383);  // i*128+j
    uint32_t bits = rbits32(keys.v[r][0], keys.v[r][1], rem, KK * KK);
    float f = bits_unif(bits);
    float u = fmaxf(TINYF, __fadd_rn(f, TINYF));
    gtab[gi] = -logf(-logf(u));
  } else {
    // proposal table: exact same ops as the in-round tid==128 block
    int gi = (b - 1033) * 256 + tid;     // 0..2047
    if (gi < NR * KK) {
      int r = gi >> 7, k = gi & 127;
      int t = NN - r;
      uint32_t h = rbits32(keys.v[r][2], keys.v[r][3], (uint32_t)k, 256u);
      uint32_t l = rbits32(keys.v[r][2], keys.v[r][3], (uint32_t)(128 + k), 256u);
      uint32_t span = (uint32_t)(t * (t - 1) / 2);
      uint32_t mult = 65536u % span;
      mult = (mult * mult) % span;
      uint32_t off = ((h % span) * mult + (l % span)) % span;
      int p = (int)off;
      int a1 = 0, rem = p, rl = t - 1;
      while (rem >= rl) { rem -= rl; ++a1; --rl; }
      pidx1[gi] = a1;
      pidx2[gi] = a1 + 1 + rem;
      uint32_t bb = rbits32(keys.v[r][4], keys.v[r][5], (uint32_t)k, 128u);
      float e1 = -log1pf(-bits_unif(bb));
      bb = rbits32(keys.v[r][6], keys.v[r][7], (uint32_t)k, 128u);
      float e2 = -log1pf(-bits_unif(bb));
      pb1[gi] = e1; pb2[gi] = e2;
      float lnp = logf((float)span);
      plvp[gi] = __fadd_rn(__fadd_rn(-lnp, -e1), -e2);
      pee1[gi] = expf(-e1);
      pee2[gi] = expf(-e2);
    }
  }
}

// seq_encoder: lane d computes emb(n,d) with the exact sequential fmaf chain.
__global__ __launch_bounds__(64) void k_emb0(const float* data, const float* Wenc,
                                             const float* Wstat, float* emb_pool,
                                             float* ew0) {
  int n = blockIdx.x, d = threadIdx.x;
  __shared__ float ne[64];
  const float* dp = data + n * 2048;
  const float* wp = Wenc + d;
  float acc = 0.0f;
#pragma unroll 32
  for (int i = 0; i < 2048; ++i) acc = fmaf(dp[i], wp[(size_t)i * 64], acc);
  float v = xla_tanh(acc);
  ne[d] = v;
  emb_pool[n * 64 + d] = v;
  __syncthreads();
  if (d < 4) {
    float s = 0.0f;
    for (int c = 0; c < 64; ++c) s = fmaf(ne[c], Wstat[c * 4 + d], s);
    ew0[n * 4 + d] = s;
  }
}

__global__ void k_leafterm(const float* fel_pool, const float* ew0,
                           const float* sitelog, float* st_pool) {
  int id = blockIdx.x * blockDim.x + threadIdx.x;
  if (id >= NN * SS) return;
  int n = id >> 9, s = id & 511;
  float lg[4], ex[4], stat[4];
  for (int a = 0; a < 4; ++a) lg[a] = __fadd_rn(ew0[n * 4 + a], sitelog[s * 4 + a]);
  float m = lg[0];
  for (int a = 1; a < 4; ++a) m = fmaxf(m, lg[a]);
  float ssum = 0.0f;
  for (int a = 0; a < 4; ++a) { ex[a] = expf(__fsub_rn(lg[a], m)); ssum = __fadd_rn(ssum, ex[a]); }
  for (int a = 0; a < 4; ++a) stat[a] = __fdiv_rn(ex[a], ssum);
  float q[4], am = -INFINITY;
  for (int a = 0; a < 4; ++a) {
    q[a] = __fadd_rn(fel_pool[n * 2048 + s * 4 + a], logf(stat[a]));
    am = fmaxf(am, q[a]);
  }
  am = fin_or0(am);
  float se = 0.0f;
  for (int a = 0; a < 4; ++a) se = __fadd_rn(se, expf(__fsub_rn(q[a], am)));
  st_pool[n * 512 + s] = __fadd_rn(logf(se), am);
}

// ---------------- the fused per-round kernel (256 threads) ----------------
__global__ __launch_bounds__(256) void k_round(
    int t, int r,
    const float* gtab, const int* pidx1, const int* pidx2,
    const float* pb1, const float* pb2, const float* plvp,
    const float* pee1, const float* pee2,
    const float* logwC, float* logwN,
    const float* logpiC, float* logpiN,
    const int* ilistC, int* ilistN,
    const int* m1C, int* m1N, const int* m2C, int* m2N,
    const float* br1C, float* br1N, const float* br2C, float* br2N,
    float* emb_pool, float* fel_pool, float* st_pool, int* lc_pool,
    const float* Wmerge, const float* Wstat, const float* sitelog,
    const float* logdf, float* logws_r, float* loglik) {
  int k = blockIdx.x, tid = threadIdx.x;
  int tn = t - 1, tn2 = t - 2;
  int newrow = NN + r * KK + k;
  __shared__ float stbuf[15 * 512];  // 30 KB
  __shared__ float cat[128];
  __shared__ float ne[64];
  __shared__ float ewl[4];
  __shared__ float smax[4];
  __shared__ int sidx[4];
  __shared__ int sI1, sI2;
  __shared__ float sB1, sB2, sLvp, sE1, sE2;
  __shared__ int ilN[16];
  __shared__ int lcb[16];
  __shared__ float brb1[15], brb2[15];

  // ---- phase 1: resample argmax (gumbels precomputed) + proposal loads ----
  float v = -INFINITY;
  if (tid < 128) {
    v = __fadd_rn(gtab[((size_t)r * KK + k) * KK + tid], logwC[tid]);
  } else if (tid == 128) {
    int gi = r * KK + k;
    sI1 = pidx1[gi];
    sI2 = pidx2[gi];
    sB1 = pb1[gi];
    sB2 = pb2[gi];
    sLvp = plvp[gi];
    sE1 = pee1[gi];
    sE2 = pee2[gi];
  }
  float m = v;
  for (int d = 32; d > 0; d >>= 1) m = fmaxf(m, __shfl_xor(m, d, 64));
  int w = tid >> 6;
  if ((tid & 63) == 0) smax[w] = m;
  __syncthreads();
  float gm = fmaxf(fmaxf(smax[0], smax[1]), fmaxf(smax[2], smax[3]));
  int cand = (v == gm) ? tid : 9999;
  for (int d = 32; d > 0; d >>= 1) {
    int o = __shfl_xor(cand, d, 64);
    cand = (o < cand) ? o : cand;
  }
  if ((tid & 63) == 0) sidx[w] = cand;
  __syncthreads();
  int a;
  {
    int b0 = (sidx[0] < sidx[1]) ? sidx[0] : sidx[1];
    int b1_ = (sidx[2] < sidx[3]) ? sidx[2] : sidx[3];
    a = (b0 < b1_) ? b0 : b1_;
  }
  int i1 = sI1, i2 = sI2;
  int p1 = ilistC[a * 16 + i1];
  int p2 = ilistC[a * 16 + i2];

  // ---- phase 2: cat load | bookkeeping ----
  if (tid < 64) {
    cat[tid] = emb_pool[p1 * 64 + tid];
    cat[64 + tid] = emb_pool[p2 * 64 + tid];
  } else if (tid >= 64 && tid < 80) {
    int pos = tid - 64;
    if (pos < tn2) {
      int src = pos + (pos >= i1) + (pos >= (i2 - 1));
      int row = ilistC[a * 16 + src];
      ilN[pos] = row;
      ilistN[k * 16 + pos] = row;
      lcb[pos] = lc_pool[row];
    } else if (pos == tn2) {
      ilN[pos] = newrow;
      ilistN[k * 16 + pos] = newrow;
      int lcnew = lc_pool[p1] + lc_pool[p2];
      lcb[pos] = lcnew;
      lc_pool[newrow] = lcnew;
    }
  } else if (tid >= 96 && tid < 96 + NR) {
    int j = tid - 96;
    if (j < r) {
      int v1 = m1C[a * 15 + j]; m1N[k * 15 + j] = v1;
      int v2 = m2C[a * 15 + j]; m2N[k * 15 + j] = v2;
      float w1 = br1C[a * 15 + j]; br1N[k * 15 + j] = w1; brb1[j] = w1;
      float w2 = br2C[a * 15 + j]; br2N[k * 15 + j] = w2; brb2[j] = w2;
    } else if (j == r) {
      m1N[k * 15 + r] = i1;
      m2N[k * 15 + r] = i2;
      br1N[k * 15 + r] = sB1;
      br2N[k * 15 + r] = sB2;
      brb1[r] = sB1;
      brb2[r] = sB2;
    }
  }
  __syncthreads();

  // ---- phase 3: newemb + ew (wave 0) | stage old st rows (tids 64..255) ----
  if (tid < 64) {
    float acc = 0.0f;
    for (int c = 0; c < 128; ++c) acc = fmaf(cat[c], Wmerge[c * 64 + tid], acc);
    float vv = xla_tanh(acc);
    ne[tid] = vv;
    emb_pool[newrow * 64 + tid] = vv;
    // same-wave LDS lockstep: ne[] writes complete before these reads
    if (tid < 4) {
      float s = 0.0f;
      for (int c = 0; c < 64; ++c) s = fmaf(ne[c], Wstat[c * 4 + tid], s);
      ewl[tid] = s;
    }
  } else {
    int nf4 = tn2 * 128;
    int base = tid - 64;  // 192 threads
    float4 tmp[10];
#pragma unroll
    for (int it = 0; it < 10; ++it) {
      int q = base + it * 192;
      if (q < nf4)
        tmp[it] = *(const float4*)(st_pool + (size_t)ilN[q >> 7] * 512 + ((q & 127) << 2));
    }
#pragma unroll
    for (int it = 0; it < 10; ++it) {
      int q = base + it * 192;
      if (q < nf4) ((float4*)stbuf)[q] = tmp[it];
    }
  }
  __syncthreads();

  // ---- phase 5: fold old rows (tid 0) || new-node Felsenstein (tids 64..255) ----
  float ll = 0.0f;
  if (tid == 0) {
    fold8(ll, (const float4*)stbuf, tn2 * 128);
  } else if (tid >= 64) {
    float e1 = sE1, e2 = sE2;
    float om1 = __fsub_rn(1.0f, e1), om2 = __fsub_rn(1.0f, e2);
    float ewv[4];
#pragma unroll
    for (int aa = 0; aa < 4; ++aa) ewv[aa] = ewl[aa];
    for (int s = tid - 64; s < 512; s += 192) {
      float lg[4], ex[4], stat[4];
#pragma unroll
      for (int aa = 0; aa < 4; ++aa) lg[aa] = __fadd_rn(ewv[aa], sitelog[s * 4 + aa]);
      float mm = lg[0];
#pragma unroll
      for (int aa = 1; aa < 4; ++aa) mm = fmaxf(mm, lg[aa]);
      float ssum = 0.0f;
#pragma unroll
      for (int aa = 0; aa < 4; ++aa) {
        ex[aa] = expf(__fsub_rn(lg[aa], mm));
        ssum = __fadd_rn(ssum, ex[aa]);
      }
#pragma unroll
      for (int aa = 0; aa < 4; ++aa) stat[aa] = __fdiv_rn(ex[aa], ssum);
      float4 f1v = *(const float4*)(fel_pool + (size_t)p1 * 2048 + s * 4);
      float4 f2v = *(const float4*)(fel_pool + (size_t)p2 * 2048 + s * 4);
      float f1a[4] = {f1v.x, f1v.y, f1v.z, f1v.w};
      float f2a[4] = {f2v.x, f2v.y, f2v.z, f2v.w};
      // deduped log P (bitwise-identical inputs; see rounds 5/6)
      float lo1[4], ld1[4], lo2[4], ld2[4];
#pragma unroll
      for (int bb = 0; bb < 4; ++bb) {
        float m1v = __fmul_rn(om1, stat[bb]);
        lo1[bb] = logf(__fadd_rn(m1v, 1e-30f));
        ld1[bb] = logf(__fadd_rn(__fadd_rn(e1, m1v), 1e-30f));
        float m2v = __fmul_rn(om2, stat[bb]);
        lo2[bb] = logf(__fadd_rn(m2v, 1e-30f));
        ld2[bb] = logf(__fadd_rn(__fadd_rn(e2, m2v), 1e-30f));
      }
      float nf[4];
#pragma unroll
      for (int aa = 0; aa < 4; ++aa) {
        float q1[4], am = -INFINITY;
#pragma unroll
        for (int bb = 0; bb < 4; ++bb) {
          q1[bb] = __fadd_rn((aa == bb) ? ld1[bb] : lo1[bb], f1a[bb]);
          am = fmaxf(am, q1[bb]);
        }
        am = fin_or0(am);
        float se = 0.0f;
#pragma unroll
        for (int bb = 0; bb < 4; ++bb) se = __fadd_rn(se, expf(__fsub_rn(q1[bb], am)));
        float h1 = __fadd_rn(logf(se), am);
        float q2[4], am2 = -INFINITY;
#pragma unroll
        for (int bb = 0; bb < 4; ++bb) {
          q2[bb] = __fadd_rn((aa == bb) ? ld2[bb] : lo2[bb], f2a[bb]);
          am2 = fmaxf(am2, q2[bb]);
        }
        am2 = fin_or0(am2);
        float se2 = 0.0f;
#pragma unroll
        for (int bb = 0; bb < 4; ++bb) se2 = __fadd_rn(se2, expf(__fsub_rn(q2[bb], am2)));
        float h2 = __fadd_rn(logf(se2), am2);
        nf[aa] = __fadd_rn(h1, h2);
      }
      *(float4*)(fel_pool + (size_t)newrow * 2048 + s * 4) =
          make_float4(nf[0], nf[1], nf[2], nf[3]);
      float q3[4], am3 = -INFINITY;
#pragma unroll
      for (int aa = 0; aa < 4; ++aa) {
        q3[aa] = __fadd_rn(nf[aa], logf(stat[aa]));
        am3 = fmaxf(am3, q3[aa]);
      }
      am3 = fin_or0(am3);
      float se3 = 0.0f;
#pragma unroll
      for (int aa = 0; aa < 4; ++aa) se3 = __fadd_rn(se3, expf(__fsub_rn(q3[aa], am3)));
      float stv = __fadd_rn(logf(se3), am3);
      stbuf[tn2 * 512 + s] = stv;
      st_pool[(size_t)newrow * 512 + s] = stv;
    }
  }
  __syncthreads();

  // ---- phase 6: fold new row + weights (tid 0) ----
  if (tid == 0) {
    fold8(ll, (const float4*)(stbuf + tn2 * 512), 128);
    float lt = 0.0f;
    for (int pos = 0; pos < tn; ++pos) {
      int idx = 2 * lcb[pos] - 3;
      if (idx < 0) idx = 0;
      lt = __fadd_rn(lt, logdf[idx]);
    }
    lt = -lt;
    float s1 = 0.0f, s2 = 0.0f;
    for (int j = 0; j <= r; ++j) {
      s1 = __fadd_rn(s1, -brb1[j]);
      s2 = __fadd_rn(s2, -brb2[j]);
    }
    float lb = __fadd_rn(s1, s2);
    float lpi = __fadd_rn(__fadd_rn(ll, lt), lb);
    float prev = logpiC[a];
    float lw = __fsub_rn(__fadd_rn(__fsub_rn(lpi, prev), 0.0f), sLvp);
    logpiN[k] = lpi;
    logwN[k] = lw;
    logws_r[k] = lw;
    loglik[k] = ll;
  }
}

// final: parallel. Exact max / first-argmax; parallel exp-sum only hits out[0].
__global__ void k_final(const float* logws, const float* loglik,
                        const int* m1D, const int* m2D,
                        const float* br1D, const float* br2D, float* out) {
  int j = threadIdx.x;  // 128
  out[1 + j] = loglik[j];
  __shared__ float sm[2];
  __shared__ float ssum[2];
  __shared__ int si[2];
  float c = logf(128.0f);
  float z = 0.0f;
  for (int r = 0; r < NR; ++r) {
    float v = __fsub_rn(logws[r * KK + j], c);
    float m = v;
    for (int d = 32; d > 0; d >>= 1) m = fmaxf(m, __shfl_xor(m, d, 64));
    if ((j & 63) == 0) sm[j >> 6] = m;
    __syncthreads();
    float gm = fin_or0(fmaxf(sm[0], sm[1]));
    float e = expf(__fsub_rn(v, gm));
    for (int d = 32; d > 0; d >>= 1) e = __fadd_rn(e, __shfl_xor(e, d, 64));
    if ((j & 63) == 0) ssum[j >> 6] = e;
    __syncthreads();
    if (j == 0) z = __fadd_rn(z, __fadd_rn(logf(__fadd_rn(ssum[0], ssum[1])), gm));
    __syncthreads();
  }
  if (j == 0) out[0] = z;
  float lv = loglik[j];
  float m2 = lv;
  for (int d = 32; d > 0; d >>= 1) m2 = fmaxf(m2, __shfl_xor(m2, d, 64));
  if ((j & 63) == 0) sm[j >> 6] = m2;
  __syncthreads();
  float gm2 = fmaxf(sm[0], sm[1]);
  int cand = (lv == gm2) ? j : 9999;
  for (int d = 32; d > 0; d >>= 1) {
    int o = __shfl_xor(cand, d, 64);
    cand = (o < cand) ? o : cand;
  }
  if ((j & 63) == 0) si[j >> 6] = cand;
  __syncthreads();
  int bi = (si[0] < si[1]) ? si[0] : si[1];
  if (j < NR) {
    out[129 + j] = (float)m1D[bi * 15 + j];
    out[144 + j] = (float)m2D[bi * 15 + j];
    out[159 + j] = br1D[bi * 15 + j];
    out[174 + j] = br2D[bi * 15 + j];
  }
}

// ---------------- host: key schedule + orchestration ----------------
static void split5_host(uint32_t* key0, uint32_t* key1, uint32_t out[8]) {
#if PARTITIONABLE
  uint32_t nk0, nk1, o0, o1;
  tf2x32(*key0, *key1, 0u, 0u, &nk0, &nk1);
  for (int j = 1; j < 5; ++j) {
    tf2x32(*key0, *key1, 0u, (uint32_t)j, &o0, &o1);
    out[2 * (j - 1)] = o0;
    out[2 * (j - 1) + 1] = o1;
  }
  *key0 = nk0; *key1 = nk1;
#else
  uint32_t a0[5], a1[5];
  for (int i = 0; i < 5; ++i) tf2x32(*key0, *key1, (uint32_t)i, (uint32_t)(i + 5), &a0[i], &a1[i]);
  uint32_t flat[10] = {a0[0], a0[1], a0[2], a0[3], a0[4], a1[0], a1[1], a1[2], a1[3], a1[4]};
  *key0 = flat[0]; *key1 = flat[1];
  for (int j = 0; j < 8; ++j) out[j] = flat[2 + j];
#endif
}

extern "C" void kernel_launch(void* const* d_in, const int* in_sizes, int n_in,
                              void* d_out, int out_size, void* d_ws, size_t ws_size,
                              hipStream_t stream) {
  const float* data = (const float*)d_in[0];
  const float* datab = (const float*)d_in[1];
  const float* Wenc = (const float*)d_in[3];
  const float* Wmerge = (const float*)d_in[4];
  const float* Wstat = (const float*)d_in[5];
  const float* Wpos = (const float*)d_in[6];
  const float* Wsite = (const float*)d_in[7];
  float* out = (float*)d_out;

  char* base = (char*)d_ws;
  size_t off = 0;
  auto alloc = [&](size_t bytes) -> void* {
    void* p = base + off;
    off += (bytes + 255) & ~(size_t)255;
    return p;
  };
  float* fel_pool = (float*)alloc((size_t)NROWS * 2048 * 4);
  float* st_pool = (float*)alloc((size_t)NROWS * 512 * 4);
  float* emb_pool = (float*)alloc((size_t)NROWS * 64 * 4);
  int* lc_pool = (int*)alloc((size_t)NROWS * 4);
  int* ilist[2]; int* m1[2]; int* m2[2]; float* br1[2]; float* br2[2];
  float* logpi[2]; float* logw2[2];
  for (int b = 0; b < 2; ++b) ilist[b] = (int*)alloc((size_t)KK * 16 * 4);
  for (int b = 0; b < 2; ++b) m1[b] = (int*)alloc((size_t)KK * 15 * 4);
  for (int b = 0; b < 2; ++b) m2[b] = (int*)alloc((size_t)KK * 15 * 4);
  for (int b = 0; b < 2; ++b) br1[b] = (float*)alloc((size_t)KK * 15 * 4);
  for (int b = 0; b < 2; ++b) br2[b] = (float*)alloc((size_t)KK * 15 * 4);
  for (int b = 0; b < 2; ++b) logpi[b] = (float*)alloc((size_t)KK * 4);
  for (int b = 0; b < 2; ++b) logw2[b] = (float*)alloc((size_t)KK * 4);
  float* logws = (float*)alloc(NR * KK * 4);
  float* loglik = (float*)alloc(KK * 4);
  float* sitelog = (float*)alloc(SS * 4 * 4);
  float* logdf = (float*)alloc(33 * 4);
  float* ew0 = (float*)alloc(NN * 4 * 4);
  float* gtab = (float*)alloc((size_t)NR * KK * KK * 4);   // 983 KB
  int* pidx1 = (int*)alloc((size_t)NR * KK * 4);
  int* pidx2 = (int*)alloc((size_t)NR * KK * 4);
  float* pb1 = (float*)alloc((size_t)NR * KK * 4);
  float* pb2 = (float*)alloc((size_t)NR * KK * 4);
  float* plvp = (float*)alloc((size_t)NR * KK * 4);
  float* pee1 = (float*)alloc((size_t)NR * KK * 4);
  float* pee2 = (float*)alloc((size_t)NR * KK * 4);
  (void)ws_size; (void)in_sizes; (void)n_in; (void)out_size;

  // precompute all round keys on host (deterministic)
  KeysAll keys;
  uint32_t key0 = 0u, key1 = 42u;  // jax.random.key(42)
  for (int r = 0; r < NR; ++r) split5_host(&key0, &key1, keys.v[r]);

  // setup (3 launches)
  k_setup<<<1041, 256, 0, stream>>>(keys, datab, Wpos, Wsite, fel_pool, sitelog,
                                    logw2[0], logpi[0], lc_pool, ilist[0], logdf,
                                    gtab, pidx1, pidx2, pb1, pb2, plvp, pee1, pee2);
  k_emb0<<<NN, 64, 0, stream>>>(data, Wenc, Wstat, emb_pool, ew0);
  k_leafterm<<<32, 256, 0, stream>>>(fel_pool, ew0, sitelog, st_pool);

  for (int r = 0; r < NR; ++r) {
    int t = NN - r;
    int cur = r & 1, nxt = cur ^ 1;
    k_round<<<KK, 256, 0, stream>>>(
        t, r, gtab, pidx1, pidx2, pb1, pb2, plvp, pee1, pee2,
        logw2[cur], logw2[nxt], logpi[cur], logpi[nxt],
        ilist[cur], ilist[nxt], m1[cur], m1[nxt], m2[cur], m2[nxt],
        br1[cur], br1[nxt], br2[cur], br2[nxt],
        emb_pool, fel_pool, st_pool, lc_pool,
        Wmerge, Wstat, sitelog, logdf, logws + r * KK, loglik);
  }
  // after r=14: nxt == 1
  k_final<<<1, 128, 0, stream>>>(logws, loglik, m1[1], m2[1], br1[1], br2[1], out);
}